// Round 9
// baseline (407.044 us; speedup 1.0000x reference)
//
#include <hip/hip_runtime.h>
#include <hip/hip_bf16.h>
#include <hip/hip_cooperative_groups.h>
#include <math.h>

namespace cg = cooperative_groups;

#define HDIM 512
#define LSEQ 1024
#define BSZ  4

typedef __attribute__((ext_vector_type(8))) short short8;
typedef __attribute__((ext_vector_type(4))) float floatx4;

__device__ __forceinline__ float2 cmul(float2 a, float2 b) {
  float2 r;
  r.x = a.x * b.x - a.y * b.y;
  r.y = a.x * b.y + a.y * b.x;
  return r;
}
__device__ __forceinline__ float2 cadd(float2 a, float2 b) {
  float2 r; r.x = a.x + b.x; r.y = a.y + b.y; return r;
}
__device__ __forceinline__ float2 cfma(float2 a, float2 b, float2 c) {
  c.x += a.x * b.x - a.y * b.y;
  c.y += a.x * b.y + a.y * b.x;
  return c;
}
__device__ __forceinline__ ushort f2bf(float f) {
  __hip_bfloat16 h = __float2bfloat16(f);
  return *(ushort*)&h;
}

struct FusedParams {
  const float *x, *nw, *nb;
  const float *lre, *lim, *pre, *pim, *bre, *bim, *cre, *cim, *dsc, *lst;
  const float *w1, *ob, *w2, *o2b;
  float* xn;
  ushort *Uhi, *Ulo, *Thi, *Tlo, *Wst;
  __hip_bfloat16* Abuf;
  float* Kbuf;
  float* out;
};

// One cooperative kernel: grid 256 x 512 threads (1 block/CU, co-resident).
// S0: LN + Wconv (blocks 0..254) || kgen (block 255)
// S1: transpose xn->U(hi/lo) + toeplitz K->T(hi/lo)
// S2: conv GEMM (dbuf LDS, triangular skip, paired tiles) + GELU epilogue
// S3: proj GEMM (dbuf LDS, dual C1/C2) + sigmoid-gate residual epilogue
__global__ __launch_bounds__(512, 2) void fused_kernel(FusedParams p) {
  __shared__ __align__(16) char smem[40960];
  cg::grid_group grid = cg::this_grid();
  const int tid = threadIdx.x;
  const int wv = tid >> 6, lane = tid & 63;
  const int blk = blockIdx.x;

  //======== Stage 0 ========
  if (blk < 255) {
    // LayerNorm: one wave per row, 8 rows/block/sweep
    for (int row = blk * 8 + wv; row < BSZ * LSEQ; row += 2040) {
      const float* xr = p.x + (size_t)row * HDIM;
      float4 v0 = ((const float4*)xr)[lane];
      float4 v1 = ((const float4*)xr)[lane + 64];
      float s  = v0.x + v0.y + v0.z + v0.w + v1.x + v1.y + v1.z + v1.w;
      float ss = v0.x*v0.x + v0.y*v0.y + v0.z*v0.z + v0.w*v0.w
               + v1.x*v1.x + v1.y*v1.y + v1.z*v1.z + v1.w*v1.w;
      #pragma unroll
      for (int m = 1; m < 64; m <<= 1) { s += __shfl_xor(s, m); ss += __shfl_xor(ss, m); }
      float mu   = s * (1.0f / HDIM);
      float var  = ss * (1.0f / HDIM) - mu * mu;
      float rstd = rsqrtf(var + 1e-5f);
      float4 w0 = ((const float4*)p.nw)[lane];
      float4 w1 = ((const float4*)p.nw)[lane + 64];
      float4 b0 = ((const float4*)p.nb)[lane];
      float4 b1 = ((const float4*)p.nb)[lane + 64];
      float4 o0, o1;
      o0.x = (v0.x - mu) * rstd * w0.x + b0.x;
      o0.y = (v0.y - mu) * rstd * w0.y + b0.y;
      o0.z = (v0.z - mu) * rstd * w0.z + b0.z;
      o0.w = (v0.w - mu) * rstd * w0.w + b0.w;
      o1.x = (v1.x - mu) * rstd * w1.x + b1.x;
      o1.y = (v1.y - mu) * rstd * w1.y + b1.y;
      o1.z = (v1.z - mu) * rstd * w1.z + b1.z;
      o1.w = (v1.w - mu) * rstd * w1.w + b1.w;
      float* xo = p.xn + (size_t)row * HDIM;
      ((float4*)xo)[lane] = o0;
      ((float4*)xo)[lane + 64] = o1;
    }
    // Weight convert (fills idle time under kgen)
    int idx = blk * 512 + tid;
    if (idx < 65536) {
      int e0 = idx * 8;
      int n = e0 >> 9, k0 = e0 & 511;
      const float* Wr = (n < 512) ? (p.w1 + (size_t)n * 512 + k0)
                                  : (p.w2 + (size_t)(n - 512) * 512 + k0);
      ushort tmp[8];
      #pragma unroll
      for (int q = 0; q < 8; q++) tmp[q] = f2bf(Wr[q]);
      *(short8*)&p.Wst[e0] = *(short8*)tmp;
    }
  } else {
    // ---- kgen: K[32a+b] = Re( (c^T (Ab^32)^a) . (Ab^b Bb) ) ----
    float2* Ldab = (float2*)smem;
    float2* Lu  = Ldab + 64;
    float2* Lr  = Lu + 64;
    float2* LBb = Lr + 64;
    float2* Rv  = LBb + 64;      // [a*64+n]
    float2* Wv  = Rv + 2048;     // [n*32+b]
    // Phase A: DPLR setup (wave 0); wave 1 inits Rv[0] = c
    if (tid < 64) {
      int n = tid;
      float step = expf(p.lst[0]);
      float g = 2.0f / step;
      float lr = p.lre[n], li = p.lim[n];
      float pr = p.pre[n], pi = p.pim[n];
      float br = p.bre[n], bi = p.bim[n];
      float den  = (g - lr) * (g - lr) + li * li;
      float dinr = (g - lr) / den, dini = li / den;
      float dabr = (g + lr) * dinr - li * dini;
      float dabi = (g + lr) * dini + li * dinr;
      float ur = dinr * pr - dini * pi;
      float ui = dinr * pi + dini * pr;
      float qr = pr * dinr + pi * dini;
      float qi = pr * dini - pi * dinr;
      float pm2 = pr * pr + pi * pi;
      float betr = pm2 * dinr, beti = pm2 * dini;
      float gar = qr * br - qi * bi;
      float gai = qr * bi + qi * br;
      #pragma unroll
      for (int m = 1; m < 64; m <<= 1) {
        betr += __shfl_xor(betr, m); beti += __shfl_xor(beti, m);
        gar  += __shfl_xor(gar, m);  gai  += __shfl_xor(gai, m);
      }
      float obr = 1.0f + betr, obi = beti;
      float ob2 = obr * obr + obi * obi;
      float kr = -2.0f * g * obr / ob2;
      float ki =  2.0f * g * obi / ob2;
      float rr = kr * qr - ki * qi;
      float ri = kr * qi + ki * qr;
      float tgr = (gar * obr + gai * obi) / ob2;
      float tgi = (gai * obr - gar * obi) / ob2;
      float dbr = dinr * br - dini * bi;
      float dbi = dinr * bi + dini * br;
      float Bbr = 2.0f * (dbr - (ur * tgr - ui * tgi));
      float Bbi = 2.0f * (dbi - (ur * tgi + ui * tgr));
      float2 t;
      t.x = dabr; t.y = dabi; Ldab[n] = t;
      t.x = ur;   t.y = ui;   Lu[n]   = t;
      t.x = rr;   t.y = ri;   Lr[n]   = t;
      t.x = Bbr;  t.y = Bbi;  LBb[n]  = t;
    }
    if (wv == 1) { float2 cc; cc.x = p.cre[lane]; cc.y = p.cim[lane]; Rv[lane] = cc; }
    __syncthreads();
    // Phase B: 64 barrier-free column chains (8 waves x 8 groups)
    int g8 = lane >> 3, q8 = lane & 7;
    int jm = wv * 8 + g8;
    float2 dab[8], u[8], rn[8], cv[8];
    #pragma unroll
    for (int ii = 0; ii < 8; ii++) {
      int n = q8 * 8 + ii;
      dab[ii] = Ldab[n]; u[ii] = Lu[n]; rn[ii] = Lr[n];
    }
    float2 rj = Lr[jm];
    #pragma unroll
    for (int ii = 0; ii < 8; ii++) {
      int n = q8 * 8 + ii;
      cv[ii] = cmul(u[ii], rj);
      if (n == jm) cv[ii] = cadd(cv[ii], dab[ii]);
    }
    for (int s = 0; s < 31; s++) {
      float2 part; part.x = 0.f; part.y = 0.f;
      #pragma unroll
      for (int ii = 0; ii < 8; ii++) part = cfma(rn[ii], cv[ii], part);
      #pragma unroll
      for (int m = 1; m < 8; m <<= 1) {
        part.x += __shfl_xor(part.x, m);
        part.y += __shfl_xor(part.y, m);
      }
      #pragma unroll
      for (int ii = 0; ii < 8; ii++) {
        float2 nc = cmul(dab[ii], cv[ii]);
        cv[ii] = cfma(u[ii], part, nc);
      }
    }
    // Phase D: W chain (wave 0, serial)
    if (wv == 0) {
      float2 dab0 = Ldab[lane], u0 = Lu[lane], r0 = Lr[lane];
      float2 w = LBb[lane];
      Wv[lane * 32 + 0] = w;
      for (int b = 1; b < 32; b++) {
        float dr = r0.x * w.x - r0.y * w.y;
        float di = r0.x * w.y + r0.y * w.x;
        #pragma unroll
        for (int m = 1; m < 64; m <<= 1) { dr += __shfl_xor(dr, m); di += __shfl_xor(di, m); }
        float2 nw2;
        nw2.x = dab0.x * w.x - dab0.y * w.y + u0.x * dr - u0.y * di;
        nw2.y = dab0.x * w.y + dab0.y * w.x + u0.x * di + u0.y * dr;
        w = nw2;
        Wv[lane * 32 + b] = w;
      }
    }
    __syncthreads();
    // Phase C: R chain (1 barrier/step), M strip in cv registers
    for (int a = 1; a < 32; a++) {
      float2 part; part.x = 0.f; part.y = 0.f;
      #pragma unroll
      for (int ii = 0; ii < 8; ii++) {
        float2 Rk = Rv[(a - 1) * 64 + q8 * 8 + ii];
        part = cfma(Rk, cv[ii], part);
      }
      #pragma unroll
      for (int m = 1; m < 8; m <<= 1) {
        part.x += __shfl_xor(part.x, m);
        part.y += __shfl_xor(part.y, m);
      }
      if (q8 == 0) Rv[a * 64 + jm] = part;
      __syncthreads();
    }
    // Phase E
    for (int midx = tid; midx < 1024; midx += 512) {
      int a = midx >> 5, b = midx & 31;
      float acc = 0.f;
      for (int n = 0; n < 64; n++) {
        float2 R = Rv[a * 64 + n];
        float2 W = Wv[n * 32 + b];
        acc += R.x * W.x - R.y * W.y;
      }
      p.Kbuf[midx] = acc;
    }
  }
  __threadfence();
  grid.sync();

  //======== Stage 1: transpose + toeplitz ========
  {
    float (*tile)[65] = (float (*)[65])smem;
    #pragma unroll
    for (int s2 = 0; s2 < 2; s2++) {
      int tt = blk * 2 + s2;
      int ht = tt & 7, lt = (tt >> 3) & 15, b = tt >> 7;
      #pragma unroll
      for (int q = 0; q < 8; q++) {
        int idx = q * 512 + tid;
        int r = idx >> 6, c = idx & 63;
        tile[r][c] = p.xn[((size_t)(b * LSEQ + lt * 64 + r)) * HDIM + ht * 64 + c];
      }
      __syncthreads();
      #pragma unroll
      for (int q = 0; q < 8; q++) {
        int idx = q * 512 + tid;
        int r = idx >> 6, c = idx & 63;
        float v = tile[c][r];
        ushort h = f2bf(v);
        float rem = v - __bfloat162float(*(__hip_bfloat16*)&h);
        ushort l = f2bf(rem);
        size_t off = ((size_t)(b * HDIM + ht * 64 + r)) * LSEQ + lt * 64 + c;
        p.Uhi[off] = h;
        p.Ulo[off] = l;
      }
      __syncthreads();
    }
    int t = blk * 4 + (tid >> 7);
    int tau0 = (tid & 127) * 8;
    ushort hi[8], lo[8];
    #pragma unroll
    for (int q = 0; q < 8; q++) {
      int tau = tau0 + q;
      float v = (tau <= t) ? p.Kbuf[t - tau] : 0.f;
      hi[q] = f2bf(v);
      float rem = v - __bfloat162float(*(__hip_bfloat16*)&hi[q]);
      lo[q] = f2bf(rem);
    }
    *(short8*)&p.Thi[(size_t)t * 1024 + tau0] = *(short8*)hi;
    *(short8*)&p.Tlo[(size_t)t * 1024 + tau0] = *(short8*)lo;
  }
  __threadfence();
  grid.sync();

  //======== Stage 2: conv GEMM ========
  {
    ushort* sbase = (ushort*)smem;     // set stride 10240: [Th][Tl][Uh][Ul] x 2560 each
    const int wm = wv >> 1, wn = wv & 1;
    const int fr = lane & 15, fq = (lane >> 4) * 8;
    const int fc = lane & 15, frq = (lane >> 4) * 4;
    const int bm0 = blk >> 5, bn = blk & 31;
    const float d = p.dsc[0];
    const int si = tid & 255;
    const int srow = si >> 2, scol = (si & 3) * 8;
    const int ldst = (tid < 256 ? 0 : 5120) + srow * 40 + scol;
    #pragma unroll 1
    for (int tp = 0; tp < 2; tp++) {
      const int bm = tp ? 15 - bm0 : bm0;
      const int KT = 2 * (bm + 1);          // paired: every block does 36 k-iters total
      const ushort *g0, *g1;
      size_t Goff;
      if (tid < 256) { g0 = p.Thi; g1 = p.Tlo; Goff = (size_t)(bm * 64 + srow) * 1024 + scol; }
      else           { g0 = p.Uhi; g1 = p.Ulo; Goff = (size_t)(bn * 64 + srow) * 1024 + scol; }
      uint4 c0 = *(const uint4*)&g0[Goff];
      uint4 c1 = *(const uint4*)&g1[Goff];
      *(uint4*)&sbase[ldst]        = c0;
      *(uint4*)&sbase[ldst + 2560] = c1;
      __syncthreads();
      floatx4 acc[2] = {};
      for (int kt = 0; kt < KT; kt++) {
        const int cur = kt & 1;
        uint4 n0 = {}, n1 = {};
        if (kt + 1 < KT) {
          n0 = *(const uint4*)&g0[Goff + (size_t)(kt + 1) * 32];
          n1 = *(const uint4*)&g1[Goff + (size_t)(kt + 1) * 32];
        }
        const ushort* sTh = sbase + cur * 10240;
        const ushort* sTl = sTh + 2560;
        const ushort* sUh = sTh + 5120;
        const ushort* sUl = sTh + 7680;
        short8 ah  = *(const short8*)&sTh[(wm * 16 + fr) * 40 + fq];
        short8 al  = *(const short8*)&sTl[(wm * 16 + fr) * 40 + fq];
        short8 bh0 = *(const short8*)&sUh[(wn * 32 + fr) * 40 + fq];
        short8 bh1 = *(const short8*)&sUh[(wn * 32 + 16 + fr) * 40 + fq];
        short8 bl0 = *(const short8*)&sUl[(wn * 32 + fr) * 40 + fq];
        short8 bl1 = *(const short8*)&sUl[(wn * 32 + 16 + fr) * 40 + fq];
        acc[0] = __builtin_amdgcn_mfma_f32_16x16x32_bf16(ah, bh0, acc[0], 0, 0, 0);
        acc[0] = __builtin_amdgcn_mfma_f32_16x16x32_bf16(al, bh0, acc[0], 0, 0, 0);
        acc[0] = __builtin_amdgcn_mfma_f32_16x16x32_bf16(ah, bl0, acc[0], 0, 0, 0);
        acc[1] = __builtin_amdgcn_mfma_f32_16x16x32_bf16(ah, bh1, acc[1], 0, 0, 0);
        acc[1] = __builtin_amdgcn_mfma_f32_16x16x32_bf16(al, bh1, acc[1], 0, 0, 0);
        acc[1] = __builtin_amdgcn_mfma_f32_16x16x32_bf16(ah, bl1, acc[1], 0, 0, 0);
        if (kt + 1 < KT) {
          ushort* dst = sbase + (cur ^ 1) * 10240;
          *(uint4*)&dst[ldst]        = n0;
          *(uint4*)&dst[ldst + 2560] = n1;
        }
        __syncthreads();
      }
      const int row0 = bm * 64 + wm * 16;
      const int col0 = bn * 64 + wn * 32;
      #pragma unroll
      for (int j = 0; j < 2; j++)
        #pragma unroll
        for (int r = 0; r < 4; r++) {
          int t = row0 + frq + r;
          int c = col0 + j * 16 + fc;
          int b = c >> 9, h = c & 511;
          size_t off = (size_t)(b * LSEQ + t) * HDIM + h;
          float y = acc[j][r] + d * p.xn[off];
          float tnh = tanhf(0.7978845608028654f * (y + 0.044715f * y * y * y));
          p.Abuf[off] = __float2bfloat16(0.5f * y * (1.0f + tnh));
        }
    }
  }
  __threadfence();
  grid.sync();

  //======== Stage 3: proj GEMM ========
  {
    ushort* sbase = (ushort*)smem;     // set stride 7680: [A][W1][W2] x 2560 each
    const int wm = wv >> 1, wn = wv & 1;
    const int fr = lane & 15, fq = (lane >> 4) * 8;
    const int fc = lane & 15, frq = (lane >> 4) * 4;
    const int si = tid & 255;
    const int srow = si >> 2, scol = (si & 3) * 8;
    const ushort* Ab = (const ushort*)p.Abuf;
    #pragma unroll 1
    for (int tp = 0; tp < 2; tp++) {
      const int tt = blk + tp * 256;
      const int bm = tt >> 3, bn = tt & 7;
      size_t Aoff  = (size_t)(bm * 64 + srow) * 512 + scol;
      size_t W1off = (size_t)(bn * 64 + srow) * 512 + scol;
      size_t W2off = (size_t)(512 + bn * 64 + srow) * 512 + scol;
      if (tid < 256) {
        *(uint4*)&sbase[srow * 40 + scol]        = *(const uint4*)&Ab[Aoff];
        *(uint4*)&sbase[5120 + srow * 40 + scol] = *(const uint4*)&p.Wst[W2off];
      } else {
        *(uint4*)&sbase[2560 + srow * 40 + scol] = *(const uint4*)&p.Wst[W1off];
      }
      __syncthreads();
      floatx4 acc1[2] = {}, acc2[2] = {};
      for (int kt = 0; kt < 16; kt++) {
        const int cur = kt & 1;
        uint4 na = {}, nwa = {};
        if (kt + 1 < 16) {
          if (tid < 256) {
            na  = *(const uint4*)&Ab[Aoff + (kt + 1) * 32];
            nwa = *(const uint4*)&p.Wst[W2off + (kt + 1) * 32];
          } else {
            nwa = *(const uint4*)&p.Wst[W1off + (kt + 1) * 32];
          }
        }
        const ushort* sA  = sbase + cur * 7680;
        const ushort* sW1 = sA + 2560;
        const ushort* sW2 = sA + 5120;
        short8 af  = *(const short8*)&sA[(wm * 16 + fr) * 40 + fq];
        short8 b10 = *(const short8*)&sW1[(wn * 32 + fr) * 40 + fq];
        short8 b11 = *(const short8*)&sW1[(wn * 32 + 16 + fr) * 40 + fq];
        short8 b20 = *(const short8*)&sW2[(wn * 32 + fr) * 40 + fq];
        short8 b21 = *(const short8*)&sW2[(wn * 32 + 16 + fr) * 40 + fq];
        acc1[0] = __builtin_amdgcn_mfma_f32_16x16x32_bf16(af, b10, acc1[0], 0, 0, 0);
        acc1[1] = __builtin_amdgcn_mfma_f32_16x16x32_bf16(af, b11, acc1[1], 0, 0, 0);
        acc2[0] = __builtin_amdgcn_mfma_f32_16x16x32_bf16(af, b20, acc2[0], 0, 0, 0);
        acc2[1] = __builtin_amdgcn_mfma_f32_16x16x32_bf16(af, b21, acc2[1], 0, 0, 0);
        if (kt + 1 < 16) {
          ushort* dst = sbase + (cur ^ 1) * 7680;
          if (tid < 256) {
            *(uint4*)&dst[srow * 40 + scol]        = na;
            *(uint4*)&dst[5120 + srow * 40 + scol] = nwa;
          } else {
            *(uint4*)&dst[2560 + srow * 40 + scol] = nwa;
          }
        }
        __syncthreads();
      }
      const int row0 = bm * 64 + wm * 16;
      const int col0 = bn * 64 + wn * 32;
      #pragma unroll
      for (int j = 0; j < 2; j++)
        #pragma unroll
        for (int r = 0; r < 4; r++) {
          int row = row0 + frq + r;
          int col = col0 + j * 16 + fc;
          float c1 = acc1[j][r] + p.ob[col];
          float c2 = acc2[j][r] + p.o2b[col];
          float gate = 1.0f / (1.0f + expf(-c2));
          size_t off = (size_t)row * HDIM + col;
          p.out[off] = p.x[off] + c1 * gate;
        }
    }
  }
}

extern "C" void kernel_launch(void* const* d_in, const int* in_sizes, int n_in,
                              void* d_out, int out_size, void* d_ws, size_t ws_size,
                              hipStream_t stream) {
  char* ws = (char*)d_ws;
  FusedParams p;
  p.x   = (const float*)d_in[0];
  p.nw  = (const float*)d_in[1];
  p.nb  = (const float*)d_in[2];
  p.lre = (const float*)d_in[3];
  p.lim = (const float*)d_in[4];
  p.pre = (const float*)d_in[5];
  p.pim = (const float*)d_in[6];
  p.bre = (const float*)d_in[7];
  p.bim = (const float*)d_in[8];
  p.cre = (const float*)d_in[9];
  p.cim = (const float*)d_in[10];
  p.dsc = (const float*)d_in[11];
  p.lst = (const float*)d_in[12];
  p.w1  = (const float*)d_in[13];
  p.ob  = (const float*)d_in[14];
  p.w2  = (const float*)d_in[15];
  p.o2b = (const float*)d_in[16];
  p.xn   = (float*)(ws);                              // 0..8MB
  p.Uhi  = (ushort*)(ws + (size_t)(8  << 20));        // 8..12MB
  p.Ulo  = (ushort*)(ws + (size_t)(12 << 20));        // 12..16MB
  p.Thi  = (ushort*)(ws + (size_t)(16 << 20));        // 16..18MB
  p.Tlo  = (ushort*)(ws + (size_t)(18 << 20));        // 18..20MB
  p.Wst  = (ushort*)(ws + (size_t)(20 << 20));        // 20..21MB
  p.Abuf = (__hip_bfloat16*)(ws + (size_t)(21 << 20));// 21..25MB
  p.Kbuf = (float*)(ws + (size_t)(25 << 20));         // 4KB
  p.out  = (float*)d_out;

  void* args[] = { &p };
  hipLaunchCooperativeKernel(reinterpret_cast<void*>(fused_kernel),
                             dim3(256), dim3(512), args, 0, stream);
}

// Round 10
// 170.000 us; speedup vs baseline: 2.3944x; 2.3944x over previous
//
#include <hip/hip_runtime.h>
#include <hip/hip_bf16.h>
#include <math.h>

#define HDIM 512
#define LSEQ 1024
#define BSZ  4

typedef __attribute__((ext_vector_type(8))) short short8;
typedef __attribute__((ext_vector_type(4))) float floatx4;

__device__ __forceinline__ float2 cmul(float2 a, float2 b) {
  float2 r;
  r.x = a.x * b.x - a.y * b.y;
  r.y = a.x * b.y + a.y * b.x;
  return r;
}
__device__ __forceinline__ float2 cadd(float2 a, float2 b) {
  float2 r; r.x = a.x + b.x; r.y = a.y + b.y; return r;
}
__device__ __forceinline__ float2 cfma(float2 a, float2 b, float2 c) {
  c.x += a.x * b.x - a.y * b.y;
  c.y += a.x * b.y + a.y * b.x;
  return c;
}
__device__ __forceinline__ ushort f2bf(float f) {
  __hip_bfloat16 h = __float2bfloat16(f);
  return *(ushort*)&h;
}

// ============ Stage 1: block 0 = kgen; blocks 1..456 = LayerNorm + wconv ============
__global__ __launch_bounds__(576) void stage1_kernel(
    const float* __restrict__ x, const float* __restrict__ nw,
    const float* __restrict__ nb, float* __restrict__ xn,
    const float* __restrict__ lre, const float* __restrict__ lim,
    const float* __restrict__ pre, const float* __restrict__ pim,
    const float* __restrict__ bre, const float* __restrict__ bim,
    const float* __restrict__ cre, const float* __restrict__ cim,
    const float* __restrict__ logstep, float* __restrict__ Kout,
    const float* __restrict__ w1, const float* __restrict__ w2,
    ushort* __restrict__ Wst) {
  __shared__ float2 Ldab[64], Lu[64], Lr[64], LBb[64];
  __shared__ float2 Rv[2048];     // [a*64+n] = (c^T (Ab^32)^a)[n]
  __shared__ float2 Wv[2048];     // [n*32+b] = (Ab^b Bb)[n]
  int tid = threadIdx.x;
  int wv = tid >> 6;              // wave 0..8
  int lane = tid & 63;

  if (blockIdx.x != 0) {
    // ---- LayerNorm: 9 rows per block, one wave per row ----
    int row = (blockIdx.x - 1) * 9 + wv;
    if (row < BSZ * LSEQ) {
      const float* xr = x + (size_t)row * HDIM;
      float4 v0 = ((const float4*)xr)[lane];
      float4 v1 = ((const float4*)xr)[lane + 64];
      float s  = v0.x + v0.y + v0.z + v0.w + v1.x + v1.y + v1.z + v1.w;
      float ss = v0.x*v0.x + v0.y*v0.y + v0.z*v0.z + v0.w*v0.w
               + v1.x*v1.x + v1.y*v1.y + v1.z*v1.z + v1.w*v1.w;
      #pragma unroll
      for (int m = 1; m < 64; m <<= 1) { s += __shfl_xor(s, m); ss += __shfl_xor(ss, m); }
      float mu   = s * (1.0f / HDIM);
      float var  = ss * (1.0f / HDIM) - mu * mu;
      float rstd = rsqrtf(var + 1e-5f);
      float4 w0 = ((const float4*)nw)[lane];
      float4 w1v = ((const float4*)nw)[lane + 64];
      float4 b0 = ((const float4*)nb)[lane];
      float4 b1 = ((const float4*)nb)[lane + 64];
      float4 o0, o1;
      o0.x = (v0.x - mu) * rstd * w0.x + b0.x;
      o0.y = (v0.y - mu) * rstd * w0.y + b0.y;
      o0.z = (v0.z - mu) * rstd * w0.z + b0.z;
      o0.w = (v0.w - mu) * rstd * w0.w + b0.w;
      o1.x = (v1.x - mu) * rstd * w1v.x + b1.x;
      o1.y = (v1.y - mu) * rstd * w1v.y + b1.y;
      o1.z = (v1.z - mu) * rstd * w1v.z + b1.z;
      o1.w = (v1.w - mu) * rstd * w1v.w + b1.w;
      float* xo = xn + (size_t)row * HDIM;
      ((float4*)xo)[lane] = o0;
      ((float4*)xo)[lane + 64] = o1;
    }
    // ---- Weight convert (fills idle time while block 0 runs kgen) ----
    int idx = (blockIdx.x - 1) * 576 + tid;
    if (idx < 65536) {
      int e0 = idx * 8;
      int n = e0 >> 9, k0 = e0 & 511;
      const float* Wr = (n < 512) ? (w1 + (size_t)n * 512 + k0)
                                  : (w2 + (size_t)(n - 512) * 512 + k0);
      ushort tmp[8];
      #pragma unroll
      for (int q = 0; q < 8; q++) tmp[q] = f2bf(Wr[q]);
      *(short8*)&Wst[e0] = *(short8*)tmp;
    }
    return;
  }

  // ================= block 0: K generation =================
  if (tid < 64) {
    int n = tid;
    float step = expf(logstep[0]);
    float g = 2.0f / step;
    float lr = lre[n], li = lim[n];
    float pr = pre[n], pi = pim[n];
    float br = bre[n], bi = bim[n];
    float den  = (g - lr) * (g - lr) + li * li;
    float dinr = (g - lr) / den, dini = li / den;
    float dabr = (g + lr) * dinr - li * dini;
    float dabi = (g + lr) * dini + li * dinr;
    float ur = dinr * pr - dini * pi;
    float ui = dinr * pi + dini * pr;
    float qr = pr * dinr + pi * dini;
    float qi = pr * dini - pi * dinr;
    float pm2 = pr * pr + pi * pi;
    float betr = pm2 * dinr, beti = pm2 * dini;
    float gar = qr * br - qi * bi;
    float gai = qr * bi + qi * br;
    #pragma unroll
    for (int m = 1; m < 64; m <<= 1) {
      betr += __shfl_xor(betr, m); beti += __shfl_xor(beti, m);
      gar  += __shfl_xor(gar, m);  gai  += __shfl_xor(gai, m);
    }
    float obr = 1.0f + betr, obi = beti;
    float ob2 = obr * obr + obi * obi;
    float kr = -2.0f * g * obr / ob2;
    float ki =  2.0f * g * obi / ob2;
    float rr = kr * qr - ki * qi;
    float ri = kr * qi + ki * qr;
    float tgr = (gar * obr + gai * obi) / ob2;
    float tgi = (gai * obr - gar * obi) / ob2;
    float dbr = dinr * br - dini * bi;
    float dbi = dinr * bi + dini * br;
    float Bbr = 2.0f * (dbr - (ur * tgr - ui * tgi));
    float Bbi = 2.0f * (dbi - (ur * tgi + ui * tgr));
    float2 t;
    t.x = dabr; t.y = dabi; Ldab[n] = t;
    t.x = ur;   t.y = ui;   Lu[n]   = t;
    t.x = rr;   t.y = ri;   Lr[n]   = t;
    t.x = Bbr;  t.y = Bbi;  LBb[n]  = t;
  }
  if (wv == 8) { float2 cc; cc.x = cre[lane]; cc.y = cim[lane]; Rv[lane] = cc; }
  __syncthreads();

  int g8 = lane >> 3;
  int q8 = lane & 7;
  int jm = wv * 8 + g8;
  float2 cv[8];

  if (wv < 8) {
    // Phase B: barrier-free column chains
    float2 dab[8], u[8], rn[8];
    #pragma unroll
    for (int ii = 0; ii < 8; ii++) {
      int n = q8 * 8 + ii;
      dab[ii] = Ldab[n]; u[ii] = Lu[n]; rn[ii] = Lr[n];
    }
    float2 rj = Lr[jm];
    #pragma unroll
    for (int ii = 0; ii < 8; ii++) {
      int n = q8 * 8 + ii;
      cv[ii] = cmul(u[ii], rj);
      if (n == jm) cv[ii] = cadd(cv[ii], dab[ii]);
    }
    for (int s = 0; s < 31; s++) {
      float2 part; part.x = 0.f; part.y = 0.f;
      #pragma unroll
      for (int ii = 0; ii < 8; ii++) part = cfma(rn[ii], cv[ii], part);
      #pragma unroll
      for (int m = 1; m < 8; m <<= 1) {
        part.x += __shfl_xor(part.x, m);
        part.y += __shfl_xor(part.y, m);
      }
      #pragma unroll
      for (int ii = 0; ii < 8; ii++) {
        float2 nc = cmul(dab[ii], cv[ii]);
        cv[ii] = cfma(u[ii], part, nc);
      }
    }
  } else {
    // Phase D (concurrent): W chain
    float2 dab0 = Ldab[lane], u0 = Lu[lane], r0 = Lr[lane];
    float2 w = LBb[lane];
    Wv[lane * 32 + 0] = w;
    for (int b = 1; b < 32; b++) {
      float dr = r0.x * w.x - r0.y * w.y;
      float di = r0.x * w.y + r0.y * w.x;
      #pragma unroll
      for (int m = 1; m < 64; m <<= 1) { dr += __shfl_xor(dr, m); di += __shfl_xor(di, m); }
      float2 nw2;
      nw2.x = dab0.x * w.x - dab0.y * w.y + u0.x * dr - u0.y * di;
      nw2.y = dab0.x * w.y + dab0.y * w.x + u0.x * di + u0.y * dr;
      w = nw2;
      Wv[lane * 32 + b] = w;
    }
  }
  __syncthreads();

  // Phase C: R chain
  for (int a = 1; a < 32; a++) {
    if (wv < 8) {
      float2 part; part.x = 0.f; part.y = 0.f;
      #pragma unroll
      for (int ii = 0; ii < 8; ii++) {
        float2 Rk = Rv[(a - 1) * 64 + q8 * 8 + ii];
        part = cfma(Rk, cv[ii], part);
      }
      #pragma unroll
      for (int m = 1; m < 8; m <<= 1) {
        part.x += __shfl_xor(part.x, m);
        part.y += __shfl_xor(part.y, m);
      }
      if (q8 == 0) Rv[a * 64 + jm] = part;
    }
    __syncthreads();
  }

  // Phase E
  for (int midx = tid; midx < 1024; midx += 576) {
    int a = midx >> 5, b = midx & 31;
    float acc = 0.f;
    for (int n = 0; n < 64; n++) {
      float2 R = Rv[a * 64 + n];
      float2 W = Wv[n * 32 + b];
      acc += R.x * W.x - R.y * W.y;
    }
    Kout[midx] = acc;
  }
}

// ---------------- Prep: transpose(xn->U) + toeplitz ----------------
// blocks [0,512): transpose; [512,1024): toeplitz.
__global__ __launch_bounds__(256) void prep_kernel(
    const float* __restrict__ xn, const float* __restrict__ K,
    ushort* __restrict__ Uhi, ushort* __restrict__ Ulo,
    ushort* __restrict__ Thi, ushort* __restrict__ Tlo) {
  __shared__ float tile[64][65];
  int blk = blockIdx.x;
  int tid = threadIdx.x;
  if (blk < 512) {
    int ht = blk & 7, lt = (blk >> 3) & 15, b = blk >> 7;
    #pragma unroll
    for (int q = 0; q < 16; q++) {
      int idx = q * 256 + tid;
      int r = idx >> 6, c = idx & 63;
      tile[r][c] = xn[((size_t)(b * LSEQ + lt * 64 + r)) * HDIM + ht * 64 + c];
    }
    __syncthreads();
    #pragma unroll
    for (int q = 0; q < 16; q++) {
      int idx = q * 256 + tid;
      int r = idx >> 6, c = idx & 63;
      float v = tile[c][r];
      ushort h = f2bf(v);
      float rem = v - __bfloat162float(*(__hip_bfloat16*)&h);
      ushort l = f2bf(rem);
      size_t off = ((size_t)(b * HDIM + ht * 64 + r)) * LSEQ + lt * 64 + c;
      Uhi[off] = h;
      Ulo[off] = l;
    }
  } else {
    int r = blk - 512;                              // 0..511
    int t = r * 2 + (tid >> 7);
    int tau0 = (tid & 127) * 8;
    ushort hi[8], lo[8];
    #pragma unroll
    for (int q = 0; q < 8; q++) {
      int tau = tau0 + q;
      float v = (tau <= t) ? K[t - tau] : 0.f;
      hi[q] = f2bf(v);
      float rem = v - __bfloat162float(*(__hip_bfloat16*)&hi[q]);
      lo[q] = f2bf(rem);
    }
    *(short8*)&Thi[(size_t)t * 1024 + tau0] = *(short8*)hi;
    *(short8*)&Tlo[(size_t)t * 1024 + tau0] = *(short8*)lo;
  }
}

// -------- Conv GEMM: dbuf LDS (1 barrier/iter), triangular skip, GELU epilogue ----
__global__ __launch_bounds__(256) void conv_gemm_kernel(
    const ushort* __restrict__ Thi, const ushort* __restrict__ Tlo,
    const ushort* __restrict__ Uhi, const ushort* __restrict__ Ulo,
    const float* __restrict__ xn, const float* __restrict__ dptr,
    __hip_bfloat16* __restrict__ A) {
  // per set: [Th][Tl][Uh][Ul] x 2560 ushorts (64 rows x 40), 2 sets
  __shared__ ushort sbuf[2 * 10240];
  int tid = threadIdx.x;
  int lane = tid & 63;
  int wv = tid >> 6;
  int wm = wv >> 1, wn = wv & 1;
  int by = blockIdx.y;                    // 0..15
  int bm = (by < 8) ? by : 23 - by;       // balanced pairing across CUs
  int bn = blockIdx.x;                    // 0..31
  floatx4 acc[2][2] = {};
  int srow = tid >> 2;
  int scol = (tid & 3) * 8;
  int ldst = srow * 40 + scol;
  int fr = lane & 15, fq = (lane >> 4) * 8;
  size_t Toff = (size_t)(bm * 64 + srow) * 1024 + scol;
  size_t Uoff = (size_t)(bn * 64 + srow) * 1024 + scol;
  int KT = 2 * (bm + 1);                  // nonzero k-tiles (tau <= t)
  // prologue: stage k-tile 0 into set 0
  {
    uint4 th = *(const uint4*)&Thi[Toff];
    uint4 tl = *(const uint4*)&Tlo[Toff];
    uint4 uh = *(const uint4*)&Uhi[Uoff];
    uint4 ul = *(const uint4*)&Ulo[Uoff];
    *(uint4*)&sbuf[ldst]        = th;
    *(uint4*)&sbuf[ldst + 2560] = tl;
    *(uint4*)&sbuf[ldst + 5120] = uh;
    *(uint4*)&sbuf[ldst + 7680] = ul;
  }
  __syncthreads();
  for (int kt = 0; kt < KT; kt++) {
    int cur = kt & 1;
    uint4 nth = {}, ntl = {}, nuh = {}, nul = {};
    if (kt + 1 < KT) {
      size_t k1 = (size_t)(kt + 1) * 32;
      nth = *(const uint4*)&Thi[Toff + k1];
      ntl = *(const uint4*)&Tlo[Toff + k1];
      nuh = *(const uint4*)&Uhi[Uoff + k1];
      nul = *(const uint4*)&Ulo[Uoff + k1];
    }
    const ushort* sTh = sbuf + cur * 10240;
    const ushort* sTl = sTh + 2560;
    const ushort* sUh = sTh + 5120;
    const ushort* sUl = sTh + 7680;
    short8 ah[2], al[2], bh[2], bl[2];
    #pragma unroll
    for (int i = 0; i < 2; i++) {
      ah[i] = *(const short8*)&sTh[(wm * 32 + i * 16 + fr) * 40 + fq];
      al[i] = *(const short8*)&sTl[(wm * 32 + i * 16 + fr) * 40 + fq];
      bh[i] = *(const short8*)&sUh[(wn * 32 + i * 16 + fr) * 40 + fq];
      bl[i] = *(const short8*)&sUl[(wn * 32 + i * 16 + fr) * 40 + fq];
    }
    #pragma unroll
    for (int i = 0; i < 2; i++)
      #pragma unroll
      for (int j = 0; j < 2; j++) {
        acc[i][j] = __builtin_amdgcn_mfma_f32_16x16x32_bf16(ah[i], bh[j], acc[i][j], 0, 0, 0);
        acc[i][j] = __builtin_amdgcn_mfma_f32_16x16x32_bf16(al[i], bh[j], acc[i][j], 0, 0, 0);
        acc[i][j] = __builtin_amdgcn_mfma_f32_16x16x32_bf16(ah[i], bl[j], acc[i][j], 0, 0, 0);
      }
    if (kt + 1 < KT) {
      ushort* dst = sbuf + (cur ^ 1) * 10240;
      *(uint4*)&dst[ldst]        = nth;
      *(uint4*)&dst[ldst + 2560] = ntl;
      *(uint4*)&dst[ldst + 5120] = nuh;
      *(uint4*)&dst[ldst + 7680] = nul;
      __syncthreads();
    }
  }
  float d = dptr[0];
  int row0 = bm * 64 + wm * 32;
  int col0 = bn * 64 + wn * 32;
  int fc = lane & 15, frq = (lane >> 4) * 4;
  #pragma unroll
  for (int i = 0; i < 2; i++)
    #pragma unroll
    for (int j = 0; j < 2; j++)
      #pragma unroll
      for (int r = 0; r < 4; r++) {
        int t = row0 + i * 16 + frq + r;
        int c = col0 + j * 16 + fc;
        int b = c >> 9, h = c & 511;
        size_t off = (size_t)(b * LSEQ + t) * HDIM + h;
        float y = acc[i][j][r] + d * xn[off];
        float tnh = tanhf(0.7978845608028654f * (y + 0.044715f * y * y * y));
        A[off] = __float2bfloat16(0.5f * y * (1.0f + tnh));
      }
}

// ---- Proj GEMM: dbuf LDS, dual C1/C2 + fused sigmoid-gate epilogue ----
__global__ __launch_bounds__(256) void proj_kernel(
    const __hip_bfloat16* __restrict__ Abuf, const ushort* __restrict__ Wst,
    const float* __restrict__ x, const float* __restrict__ ob,
    const float* __restrict__ o2b, float* __restrict__ out) {
  // per set: [A][W1][W2] x 2560 ushorts, 2 sets
  __shared__ ushort sbuf[2 * 7680];
  int tid = threadIdx.x;
  int lane = tid & 63;
  int wv = tid >> 6;
  int wm = wv >> 1, wn = wv & 1;
  int bm = blockIdx.y, bn = blockIdx.x;   // bm<64, bn<8
  int srow = tid >> 2;
  int scol = (tid & 3) * 8;
  int ldst = srow * 40 + scol;
  int fr = lane & 15, fq = (lane >> 4) * 8;
  floatx4 acc1[2][2] = {}, acc2[2][2] = {};
  const ushort* Ab = (const ushort*)Abuf;
  size_t Aoff  = (size_t)(bm * 64 + srow) * 512 + scol;
  size_t W1off = (size_t)(bn * 64 + srow) * 512 + scol;
  size_t W2off = W1off + (size_t)512 * 512;
  {
    uint4 a0 = *(const uint4*)&Ab[Aoff];
    uint4 v1 = *(const uint4*)&Wst[W1off];
    uint4 v2 = *(const uint4*)&Wst[W2off];
    *(uint4*)&sbuf[ldst]        = a0;
    *(uint4*)&sbuf[ldst + 2560] = v1;
    *(uint4*)&sbuf[ldst + 5120] = v2;
  }
  __syncthreads();
  for (int kt = 0; kt < 16; kt++) {
    int cur = kt & 1;
    uint4 na = {}, n1 = {}, n2 = {};
    if (kt + 1 < 16) {
      int k1 = (kt + 1) * 32;
      na = *(const uint4*)&Ab[Aoff + k1];
      n1 = *(const uint4*)&Wst[W1off + k1];
      n2 = *(const uint4*)&Wst[W2off + k1];
    }
    const ushort* sA  = sbuf + cur * 7680;
    const ushort* sW1 = sA + 2560;
    const ushort* sW2 = sA + 5120;
    short8 af[2], b1[2], b2[2];
    #pragma unroll
    for (int i = 0; i < 2; i++) {
      af[i] = *(const short8*)&sA[(wm * 32 + i * 16 + fr) * 40 + fq];
      b1[i] = *(const short8*)&sW1[(wn * 32 + i * 16 + fr) * 40 + fq];
      b2[i] = *(const short8*)&sW2[(wn * 32 + i * 16 + fr) * 40 + fq];
    }
    #pragma unroll
    for (int i = 0; i < 2; i++)
      #pragma unroll
      for (int j = 0; j < 2; j++) {
        acc1[i][j] = __builtin_amdgcn_mfma_f32_16x16x32_bf16(af[i], b1[j], acc1[i][j], 0, 0, 0);
        acc2[i][j] = __builtin_amdgcn_mfma_f32_16x16x32_bf16(af[i], b2[j], acc2[i][j], 0, 0, 0);
      }
    if (kt + 1 < 16) {
      ushort* dst = sbuf + (cur ^ 1) * 7680;
      *(uint4*)&dst[ldst]        = na;
      *(uint4*)&dst[ldst + 2560] = n1;
      *(uint4*)&dst[ldst + 5120] = n2;
      __syncthreads();
    }
  }
  int row0 = bm * 64 + wm * 32;
  int col0 = bn * 64 + wn * 32;
  int fc = lane & 15, frq = (lane >> 4) * 4;
  #pragma unroll
  for (int i = 0; i < 2; i++)
    #pragma unroll
    for (int j = 0; j < 2; j++)
      #pragma unroll
      for (int r = 0; r < 4; r++) {
        int row = row0 + i * 16 + frq + r;
        int col = col0 + j * 16 + fc;
        float c1 = acc1[i][j][r] + ob[col];
        float c2 = acc2[i][j][r] + o2b[col];
        float gate = 1.0f / (1.0f + expf(-c2));
        size_t off = (size_t)row * HDIM + col;
        out[off] = x[off] + c1 * gate;
      }
}

extern "C" void kernel_launch(void* const* d_in, const int* in_sizes, int n_in,
                              void* d_out, int out_size, void* d_ws, size_t ws_size,
                              hipStream_t stream) {
  const float* x   = (const float*)d_in[0];
  const float* nw  = (const float*)d_in[1];
  const float* nb  = (const float*)d_in[2];
  const float* lre = (const float*)d_in[3];
  const float* lim = (const float*)d_in[4];
  const float* pre = (const float*)d_in[5];
  const float* pim = (const float*)d_in[6];
  const float* bre = (const float*)d_in[7];
  const float* bim = (const float*)d_in[8];
  const float* cre = (const float*)d_in[9];
  const float* cim = (const float*)d_in[10];
  const float* dsc = (const float*)d_in[11];
  const float* lst = (const float*)d_in[12];
  const float* w1  = (const float*)d_in[13];
  const float* ob  = (const float*)d_in[14];
  const float* w2  = (const float*)d_in[15];
  const float* o2b = (const float*)d_in[16];

  char* ws = (char*)d_ws;
  float* xn    = (float*)(ws);                          // 0..8MB
  ushort* Uhi  = (ushort*)(ws + (size_t)(8  << 20));    // 8..12MB
  ushort* Ulo  = (ushort*)(ws + (size_t)(12 << 20));    // 12..16MB
  ushort* Thi  = (ushort*)(ws + (size_t)(16 << 20));    // 16..18MB
  ushort* Tlo  = (ushort*)(ws + (size_t)(18 << 20));    // 18..20MB
  ushort* Wst  = (ushort*)(ws + (size_t)(20 << 20));    // 20..21MB
  __hip_bfloat16* Abuf = (__hip_bfloat16*)(ws + (size_t)(21 << 20)); // 21..25MB
  float* Kbuf  = (float*)(ws + (size_t)(25 << 20));     // 4KB
  float* out   = (float*)d_out;

  stage1_kernel<<<dim3(457), dim3(576), 0, stream>>>(x, nw, nb, xn,
                                                     lre, lim, pre, pim, bre, bim,
                                                     cre, cim, lst, Kbuf,
                                                     w1, w2, Wst);
  prep_kernel<<<dim3(1024), dim3(256), 0, stream>>>(xn, Kbuf, Uhi, Ulo, Thi, Tlo);
  conv_gemm_kernel<<<dim3(32, 16), dim3(256), 0, stream>>>(Thi, Tlo, Uhi, Ulo,
                                                           xn, dsc, Abuf);
  proj_kernel<<<dim3(8, 64), dim3(256), 0, stream>>>(Abuf, Wst, x, ob, o2b, out);
}

// Round 11
// 165.468 us; speedup vs baseline: 2.4600x; 1.0274x over previous
//
#include <hip/hip_runtime.h>
#include <hip/hip_bf16.h>
#include <math.h>

#define HDIM 512
#define LSEQ 1024
#define BSZ  4

typedef __attribute__((ext_vector_type(8))) short short8;
typedef __attribute__((ext_vector_type(4))) float floatx4;

__device__ __forceinline__ float2 cmul(float2 a, float2 b) {
  float2 r;
  r.x = a.x * b.x - a.y * b.y;
  r.y = a.x * b.y + a.y * b.x;
  return r;
}
__device__ __forceinline__ float2 cadd(float2 a, float2 b) {
  float2 r; r.x = a.x + b.x; r.y = a.y + b.y; return r;
}
__device__ __forceinline__ float2 cfma(float2 a, float2 b, float2 c) {
  c.x += a.x * b.x - a.y * b.y;
  c.y += a.x * b.y + a.y * b.x;
  return c;
}
__device__ __forceinline__ ushort f2bf(float f) {
  __hip_bfloat16 h = __float2bfloat16(f);
  return *(ushort*)&h;
}

// ============ Stage 1: block 0 = kgen; blocks 1..456 = LayerNorm + wconv ============
__global__ __launch_bounds__(576) void stage1_kernel(
    const float* __restrict__ x, const float* __restrict__ nw,
    const float* __restrict__ nb, float* __restrict__ xn,
    const float* __restrict__ lre, const float* __restrict__ lim,
    const float* __restrict__ pre, const float* __restrict__ pim,
    const float* __restrict__ bre, const float* __restrict__ bim,
    const float* __restrict__ cre, const float* __restrict__ cim,
    const float* __restrict__ logstep, float* __restrict__ Kout,
    const float* __restrict__ w1, const float* __restrict__ w2,
    ushort* __restrict__ Wst) {
  __shared__ float2 Ldab[64], Lu[64], Lr[64], LBb[64];
  __shared__ float2 Rv[2048];     // [a*64+n] = (c^T (Ab^32)^a)[n]
  __shared__ float2 Wv[2048];     // [n*32+b] = (Ab^b Bb)[n]
  int tid = threadIdx.x;
  int wv = tid >> 6;              // wave 0..8
  int lane = tid & 63;

  if (blockIdx.x != 0) {
    // ---- LayerNorm: 9 rows per block, one wave per row ----
    int row = (blockIdx.x - 1) * 9 + wv;
    if (row < BSZ * LSEQ) {
      const float* xr = x + (size_t)row * HDIM;
      float4 v0 = ((const float4*)xr)[lane];
      float4 v1 = ((const float4*)xr)[lane + 64];
      float s  = v0.x + v0.y + v0.z + v0.w + v1.x + v1.y + v1.z + v1.w;
      float ss = v0.x*v0.x + v0.y*v0.y + v0.z*v0.z + v0.w*v0.w
               + v1.x*v1.x + v1.y*v1.y + v1.z*v1.z + v1.w*v1.w;
      #pragma unroll
      for (int m = 1; m < 64; m <<= 1) { s += __shfl_xor(s, m); ss += __shfl_xor(ss, m); }
      float mu   = s * (1.0f / HDIM);
      float var  = ss * (1.0f / HDIM) - mu * mu;
      float rstd = rsqrtf(var + 1e-5f);
      float4 w0 = ((const float4*)nw)[lane];
      float4 w1v = ((const float4*)nw)[lane + 64];
      float4 b0 = ((const float4*)nb)[lane];
      float4 b1 = ((const float4*)nb)[lane + 64];
      float4 o0, o1;
      o0.x = (v0.x - mu) * rstd * w0.x + b0.x;
      o0.y = (v0.y - mu) * rstd * w0.y + b0.y;
      o0.z = (v0.z - mu) * rstd * w0.z + b0.z;
      o0.w = (v0.w - mu) * rstd * w0.w + b0.w;
      o1.x = (v1.x - mu) * rstd * w1v.x + b1.x;
      o1.y = (v1.y - mu) * rstd * w1v.y + b1.y;
      o1.z = (v1.z - mu) * rstd * w1v.z + b1.z;
      o1.w = (v1.w - mu) * rstd * w1v.w + b1.w;
      float* xo = xn + (size_t)row * HDIM;
      ((float4*)xo)[lane] = o0;
      ((float4*)xo)[lane + 64] = o1;
    }
    // ---- Weight convert (fills idle time while block 0 runs kgen) ----
    int idx = (blockIdx.x - 1) * 576 + tid;
    if (idx < 65536) {
      int e0 = idx * 8;
      int n = e0 >> 9, k0 = e0 & 511;
      const float* Wr = (n < 512) ? (w1 + (size_t)n * 512 + k0)
                                  : (w2 + (size_t)(n - 512) * 512 + k0);
      ushort tmp[8];
      #pragma unroll
      for (int q = 0; q < 8; q++) tmp[q] = f2bf(Wr[q]);
      *(short8*)&Wst[e0] = *(short8*)tmp;
    }
    return;
  }

  // ================= block 0: K generation =================
  if (tid < 64) {
    int n = tid;
    float step = expf(logstep[0]);
    float g = 2.0f / step;
    float lr = lre[n], li = lim[n];
    float pr = pre[n], pi = pim[n];
    float br = bre[n], bi = bim[n];
    float den  = (g - lr) * (g - lr) + li * li;
    float dinr = (g - lr) / den, dini = li / den;
    float dabr = (g + lr) * dinr - li * dini;
    float dabi = (g + lr) * dini + li * dinr;
    float ur = dinr * pr - dini * pi;
    float ui = dinr * pi + dini * pr;
    float qr = pr * dinr + pi * dini;
    float qi = pr * dini - pi * dinr;
    float pm2 = pr * pr + pi * pi;
    float betr = pm2 * dinr, beti = pm2 * dini;
    float gar = qr * br - qi * bi;
    float gai = qr * bi + qi * br;
    #pragma unroll
    for (int m = 1; m < 64; m <<= 1) {
      betr += __shfl_xor(betr, m); beti += __shfl_xor(beti, m);
      gar  += __shfl_xor(gar, m);  gai  += __shfl_xor(gai, m);
    }
    float obr = 1.0f + betr, obi = beti;
    float ob2 = obr * obr + obi * obi;
    float kr = -2.0f * g * obr / ob2;
    float ki =  2.0f * g * obi / ob2;
    float rr = kr * qr - ki * qi;
    float ri = kr * qi + ki * qr;
    float tgr = (gar * obr + gai * obi) / ob2;
    float tgi = (gai * obr - gar * obi) / ob2;
    float dbr = dinr * br - dini * bi;
    float dbi = dinr * bi + dini * br;
    float Bbr = 2.0f * (dbr - (ur * tgr - ui * tgi));
    float Bbi = 2.0f * (dbi - (ur * tgi + ui * tgr));
    float2 t;
    t.x = dabr; t.y = dabi; Ldab[n] = t;
    t.x = ur;   t.y = ui;   Lu[n]   = t;
    t.x = rr;   t.y = ri;   Lr[n]   = t;
    t.x = Bbr;  t.y = Bbi;  LBb[n]  = t;
  }
  if (wv == 8) { float2 cc; cc.x = cre[lane]; cc.y = cim[lane]; Rv[lane] = cc; }
  __syncthreads();

  int g8 = lane >> 3;
  int q8 = lane & 7;
  int jm = wv * 8 + g8;
  float2 cv[8];

  if (wv < 8) {
    // Phase B: barrier-free column chains
    float2 dab[8], u[8], rn[8];
    #pragma unroll
    for (int ii = 0; ii < 8; ii++) {
      int n = q8 * 8 + ii;
      dab[ii] = Ldab[n]; u[ii] = Lu[n]; rn[ii] = Lr[n];
    }
    float2 rj = Lr[jm];
    #pragma unroll
    for (int ii = 0; ii < 8; ii++) {
      int n = q8 * 8 + ii;
      cv[ii] = cmul(u[ii], rj);
      if (n == jm) cv[ii] = cadd(cv[ii], dab[ii]);
    }
    for (int s = 0; s < 31; s++) {
      float2 part; part.x = 0.f; part.y = 0.f;
      #pragma unroll
      for (int ii = 0; ii < 8; ii++) part = cfma(rn[ii], cv[ii], part);
      #pragma unroll
      for (int m = 1; m < 8; m <<= 1) {
        part.x += __shfl_xor(part.x, m);
        part.y += __shfl_xor(part.y, m);
      }
      #pragma unroll
      for (int ii = 0; ii < 8; ii++) {
        float2 nc = cmul(dab[ii], cv[ii]);
        cv[ii] = cfma(u[ii], part, nc);
      }
    }
  } else {
    // Phase D (concurrent): W chain
    float2 dab0 = Ldab[lane], u0 = Lu[lane], r0 = Lr[lane];
    float2 w = LBb[lane];
    Wv[lane * 32 + 0] = w;
    for (int b = 1; b < 32; b++) {
      float dr = r0.x * w.x - r0.y * w.y;
      float di = r0.x * w.y + r0.y * w.x;
      #pragma unroll
      for (int m = 1; m < 64; m <<= 1) { dr += __shfl_xor(dr, m); di += __shfl_xor(di, m); }
      float2 nw2;
      nw2.x = dab0.x * w.x - dab0.y * w.y + u0.x * dr - u0.y * di;
      nw2.y = dab0.x * w.y + dab0.y * w.x + u0.x * di + u0.y * dr;
      w = nw2;
      Wv[lane * 32 + b] = w;
    }
  }
  __syncthreads();

  // Phase C: R chain
  for (int a = 1; a < 32; a++) {
    if (wv < 8) {
      float2 part; part.x = 0.f; part.y = 0.f;
      #pragma unroll
      for (int ii = 0; ii < 8; ii++) {
        float2 Rk = Rv[(a - 1) * 64 + q8 * 8 + ii];
        part = cfma(Rk, cv[ii], part);
      }
      #pragma unroll
      for (int m = 1; m < 8; m <<= 1) {
        part.x += __shfl_xor(part.x, m);
        part.y += __shfl_xor(part.y, m);
      }
      if (q8 == 0) Rv[a * 64 + jm] = part;
    }
    __syncthreads();
  }

  // Phase E
  for (int midx = tid; midx < 1024; midx += 576) {
    int a = midx >> 5, b = midx & 31;
    float acc = 0.f;
    for (int n = 0; n < 64; n++) {
      float2 R = Rv[a * 64 + n];
      float2 W = Wv[n * 32 + b];
      acc += R.x * W.x - R.y * W.y;
    }
    Kout[midx] = acc;
  }
}

// ---------------- Prep: transpose(xn->Uhi) + toeplitz(K->Thi/Tlo) ----------------
// blocks [0,512): transpose; [512,1024): toeplitz.
__global__ __launch_bounds__(256) void prep_kernel(
    const float* __restrict__ xn, const float* __restrict__ K,
    ushort* __restrict__ Uhi,
    ushort* __restrict__ Thi, ushort* __restrict__ Tlo) {
  __shared__ float tile[64][65];
  int blk = blockIdx.x;
  int tid = threadIdx.x;
  if (blk < 512) {
    int ht = blk & 7, lt = (blk >> 3) & 15, b = blk >> 7;
    #pragma unroll
    for (int q = 0; q < 16; q++) {
      int idx = q * 256 + tid;
      int r = idx >> 6, c = idx & 63;
      tile[r][c] = xn[((size_t)(b * LSEQ + lt * 64 + r)) * HDIM + ht * 64 + c];
    }
    __syncthreads();
    #pragma unroll
    for (int q = 0; q < 16; q++) {
      int idx = q * 256 + tid;
      int r = idx >> 6, c = idx & 63;
      size_t off = ((size_t)(b * HDIM + ht * 64 + r)) * LSEQ + lt * 64 + c;
      Uhi[off] = f2bf(tile[c][r]);
    }
  } else {
    int r = blk - 512;                              // 0..511
    int t = r * 2 + (tid >> 7);
    int tau0 = (tid & 127) * 8;
    ushort hi[8], lo[8];
    #pragma unroll
    for (int q = 0; q < 8; q++) {
      int tau = tau0 + q;
      float v = (tau <= t) ? K[t - tau] : 0.f;
      hi[q] = f2bf(v);
      float rem = v - __bfloat162float(*(__hip_bfloat16*)&hi[q]);
      lo[q] = f2bf(rem);
    }
    *(short8*)&Thi[(size_t)t * 1024 + tau0] = *(short8*)hi;
    *(short8*)&Tlo[(size_t)t * 1024 + tau0] = *(short8*)lo;
  }
}

// -------- Conv GEMM: Y = (Thi+Tlo)*Uhi, dbuf LDS, triangular skip, GELU epilogue ----
__global__ __launch_bounds__(256) void conv_gemm_kernel(
    const ushort* __restrict__ Thi, const ushort* __restrict__ Tlo,
    const ushort* __restrict__ Uhi,
    const float* __restrict__ xn, const float* __restrict__ dptr,
    __hip_bfloat16* __restrict__ A) {
  // per set: [Th][Tl][Uh] x 2560 ushorts (64 rows x 40), 2 sets
  __shared__ ushort sbuf[2 * 7680];
  int tid = threadIdx.x;
  int lane = tid & 63;
  int wv = tid >> 6;
  int wm = wv >> 1, wn = wv & 1;
  int by = blockIdx.y;                    // 0..15
  int bm = (by < 8) ? by : 23 - by;       // balanced pairing across CUs
  int bn = blockIdx.x;                    // 0..31
  floatx4 acc[2][2] = {};
  int srow = tid >> 2;
  int scol = (tid & 3) * 8;
  int ldst = srow * 40 + scol;
  int fr = lane & 15, fq = (lane >> 4) * 8;
  size_t Toff = (size_t)(bm * 64 + srow) * 1024 + scol;
  size_t Uoff = (size_t)(bn * 64 + srow) * 1024 + scol;
  int KT = 2 * (bm + 1);                  // nonzero k-tiles (tau <= t)
  {
    uint4 th = *(const uint4*)&Thi[Toff];
    uint4 tl = *(const uint4*)&Tlo[Toff];
    uint4 uh = *(const uint4*)&Uhi[Uoff];
    *(uint4*)&sbuf[ldst]        = th;
    *(uint4*)&sbuf[ldst + 2560] = tl;
    *(uint4*)&sbuf[ldst + 5120] = uh;
  }
  __syncthreads();
  for (int kt = 0; kt < KT; kt++) {
    int cur = kt & 1;
    uint4 nth = {}, ntl = {}, nuh = {};
    if (kt + 1 < KT) {
      size_t k1 = (size_t)(kt + 1) * 32;
      nth = *(const uint4*)&Thi[Toff + k1];
      ntl = *(const uint4*)&Tlo[Toff + k1];
      nuh = *(const uint4*)&Uhi[Uoff + k1];
    }
    const ushort* sTh = sbuf + cur * 7680;
    const ushort* sTl = sTh + 2560;
    const ushort* sUh = sTh + 5120;
    short8 ah[2], al[2], bh[2];
    #pragma unroll
    for (int i = 0; i < 2; i++) {
      ah[i] = *(const short8*)&sTh[(wm * 32 + i * 16 + fr) * 40 + fq];
      al[i] = *(const short8*)&sTl[(wm * 32 + i * 16 + fr) * 40 + fq];
      bh[i] = *(const short8*)&sUh[(wn * 32 + i * 16 + fr) * 40 + fq];
    }
    #pragma unroll
    for (int i = 0; i < 2; i++)
      #pragma unroll
      for (int j = 0; j < 2; j++) {
        acc[i][j] = __builtin_amdgcn_mfma_f32_16x16x32_bf16(ah[i], bh[j], acc[i][j], 0, 0, 0);
        acc[i][j] = __builtin_amdgcn_mfma_f32_16x16x32_bf16(al[i], bh[j], acc[i][j], 0, 0, 0);
      }
    if (kt + 1 < KT) {
      ushort* dst = sbuf + (cur ^ 1) * 7680;
      *(uint4*)&dst[ldst]        = nth;
      *(uint4*)&dst[ldst + 2560] = ntl;
      *(uint4*)&dst[ldst + 5120] = nuh;
      __syncthreads();
    }
  }
  float d = dptr[0];
  int row0 = bm * 64 + wm * 32;
  int col0 = bn * 64 + wn * 32;
  int fc = lane & 15, frq = (lane >> 4) * 4;
  #pragma unroll
  for (int i = 0; i < 2; i++)
    #pragma unroll
    for (int j = 0; j < 2; j++)
      #pragma unroll
      for (int r = 0; r < 4; r++) {
        int t = row0 + i * 16 + frq + r;
        int c = col0 + j * 16 + fc;
        int b = c >> 9, h = c & 511;
        size_t off = (size_t)(b * LSEQ + t) * HDIM + h;
        float y = acc[i][j][r] + d * xn[off];
        float tnh = tanhf(0.7978845608028654f * (y + 0.044715f * y * y * y));
        A[off] = __float2bfloat16(0.5f * y * (1.0f + tnh));
      }
}

// ---- Proj GEMM: dbuf LDS, dual C1/C2 + fused sigmoid-gate epilogue ----
__global__ __launch_bounds__(256) void proj_kernel(
    const __hip_bfloat16* __restrict__ Abuf, const ushort* __restrict__ Wst,
    const float* __restrict__ x, const float* __restrict__ ob,
    const float* __restrict__ o2b, float* __restrict__ out) {
  // per set: [A][W1][W2] x 2560 ushorts, 2 sets
  __shared__ ushort sbuf[2 * 7680];
  int tid = threadIdx.x;
  int lane = tid & 63;
  int wv = tid >> 6;
  int wm = wv >> 1, wn = wv & 1;
  int bm = blockIdx.y, bn = blockIdx.x;   // bm<64, bn<8
  int srow = tid >> 2;
  int scol = (tid & 3) * 8;
  int ldst = srow * 40 + scol;
  int fr = lane & 15, fq = (lane >> 4) * 8;
  floatx4 acc1[2][2] = {}, acc2[2][2] = {};
  const ushort* Ab = (const ushort*)Abuf;
  size_t Aoff  = (size_t)(bm * 64 + srow) * 512 + scol;
  size_t W1off = (size_t)(bn * 64 + srow) * 512 + scol;
  size_t W2off = W1off + (size_t)512 * 512;
  {
    uint4 a0 = *(const uint4*)&Ab[Aoff];
    uint4 v1 = *(const uint4*)&Wst[W1off];
    uint4 v2 = *(const uint4*)&Wst[W2off];
    *(uint4*)&sbuf[ldst]        = a0;
    *(uint4*)&sbuf[ldst + 2560] = v1;
    *(uint4*)&sbuf[ldst + 5120] = v2;
  }
  __syncthreads();
  for (int kt = 0; kt < 16; kt++) {
    int cur = kt & 1;
    uint4 na = {}, n1 = {}, n2 = {};
    if (kt + 1 < 16) {
      int k1 = (kt + 1) * 32;
      na = *(const uint4*)&Ab[Aoff + k1];
      n1 = *(const uint4*)&Wst[W1off + k1];
      n2 = *(const uint4*)&Wst[W2off + k1];
    }
    const ushort* sA  = sbuf + cur * 7680;
    const ushort* sW1 = sA + 2560;
    const ushort* sW2 = sA + 5120;
    short8 af[2], b1[2], b2[2];
    #pragma unroll
    for (int i = 0; i < 2; i++) {
      af[i] = *(const short8*)&sA[(wm * 32 + i * 16 + fr) * 40 + fq];
      b1[i] = *(const short8*)&sW1[(wn * 32 + i * 16 + fr) * 40 + fq];
      b2[i] = *(const short8*)&sW2[(wn * 32 + i * 16 + fr) * 40 + fq];
    }
    #pragma unroll
    for (int i = 0; i < 2; i++)
      #pragma unroll
      for (int j = 0; j < 2; j++) {
        acc1[i][j] = __builtin_amdgcn_mfma_f32_16x16x32_bf16(af[i], b1[j], acc1[i][j], 0, 0, 0);
        acc2[i][j] = __builtin_amdgcn_mfma_f32_16x16x32_bf16(af[i], b2[j], acc2[i][j], 0, 0, 0);
      }
    if (kt + 1 < 16) {
      ushort* dst = sbuf + (cur ^ 1) * 7680;
      *(uint4*)&dst[ldst]        = na;
      *(uint4*)&dst[ldst + 2560] = n1;
      *(uint4*)&dst[ldst + 5120] = n2;
      __syncthreads();
    }
  }
  int row0 = bm * 64 + wm * 32;
  int col0 = bn * 64 + wn * 32;
  int fc = lane & 15, frq = (lane >> 4) * 4;
  #pragma unroll
  for (int i = 0; i < 2; i++)
    #pragma unroll
    for (int j = 0; j < 2; j++)
      #pragma unroll
      for (int r = 0; r < 4; r++) {
        int row = row0 + i * 16 + frq + r;
        int col = col0 + j * 16 + fc;
        float c1 = acc1[i][j][r] + ob[col];
        float c2 = acc2[i][j][r] + o2b[col];
        float gate = 1.0f / (1.0f + expf(-c2));
        size_t off = (size_t)row * HDIM + col;
        out[off] = x[off] + c1 * gate;
      }
}

extern "C" void kernel_launch(void* const* d_in, const int* in_sizes, int n_in,
                              void* d_out, int out_size, void* d_ws, size_t ws_size,
                              hipStream_t stream) {
  const float* x   = (const float*)d_in[0];
  const float* nw  = (const float*)d_in[1];
  const float* nb  = (const float*)d_in[2];
  const float* lre = (const float*)d_in[3];
  const float* lim = (const float*)d_in[4];
  const float* pre = (const float*)d_in[5];
  const float* pim = (const float*)d_in[6];
  const float* bre = (const float*)d_in[7];
  const float* bim = (const float*)d_in[8];
  const float* cre = (const float*)d_in[9];
  const float* cim = (const float*)d_in[10];
  const float* dsc = (const float*)d_in[11];
  const float* lst = (const float*)d_in[12];
  const float* w1  = (const float*)d_in[13];
  const float* ob  = (const float*)d_in[14];
  const float* w2  = (const float*)d_in[15];
  const float* o2b = (const float*)d_in[16];

  char* ws = (char*)d_ws;
  float* xn    = (float*)(ws);                          // 0..8MB
  ushort* Uhi  = (ushort*)(ws + (size_t)(8  << 20));    // 8..12MB
  ushort* Thi  = (ushort*)(ws + (size_t)(12 << 20));    // 12..14MB
  ushort* Tlo  = (ushort*)(ws + (size_t)(14 << 20));    // 14..16MB
  ushort* Wst  = (ushort*)(ws + (size_t)(16 << 20));    // 16..17MB
  __hip_bfloat16* Abuf = (__hip_bfloat16*)(ws + (size_t)(17 << 20)); // 17..21MB
  float* Kbuf  = (float*)(ws + (size_t)(21 << 20));     // 4KB
  float* out   = (float*)d_out;

  stage1_kernel<<<dim3(457), dim3(576), 0, stream>>>(x, nw, nb, xn,
                                                     lre, lim, pre, pim, bre, bim,
                                                     cre, cim, lst, Kbuf,
                                                     w1, w2, Wst);
  prep_kernel<<<dim3(1024), dim3(256), 0, stream>>>(xn, Kbuf, Uhi, Thi, Tlo);
  conv_gemm_kernel<<<dim3(32, 16), dim3(256), 0, stream>>>(Thi, Tlo, Uhi,
                                                           xn, dsc, Abuf);
  proj_kernel<<<dim3(8, 64), dim3(256), 0, stream>>>(Abuf, Wst, x, ob, o2b, out);
}